// Round 1
// baseline (292.421 us; speedup 1.0000x reference)
//
#include <hip/hip_runtime.h>
#include <hip/hip_bf16.h>

#define DIM 768
#define NHEADS 12
#define NTOK 197
#define NP 208      // padded tokens (13*16)
#define PS 232      // P LDS row stride (shorts), 16B-aligned rows
#define M_ROWS 12608   // B*N
#define M_PAD 12672    // 99*128
#define HEADS_TOT 768  // B*H

typedef __attribute__((ext_vector_type(8))) short bf16x8;
typedef __attribute__((ext_vector_type(4))) float f32x4;

__device__ inline short f2bf(float f) {
  union { __hip_bfloat16 h; short s; } u;
  u.h = __float2bfloat16(f);
  return u.s;
}

// ---------------- convert fp32 -> bf16 (x, qkv_weight, proj_weight) ----------------
__global__ void convert_kernel(const float* __restrict__ x, const float* __restrict__ wq,
                               const float* __restrict__ wp,
                               short* __restrict__ xb, short* __restrict__ wqb,
                               short* __restrict__ wpb) {
  int idx = blockIdx.x * 256 + threadIdx.x;
  const int n_x  = M_ROWS * DIM / 4;       // 2,420,736
  const int n_wq = 3 * DIM * DIM / 4;      // 442,368
  const int n_wp = DIM * DIM / 4;          // 147,456
  const float4* src; short* dst; int off;
  if (idx < n_x)                { src = (const float4*)x;  dst = xb;  off = idx; }
  else if (idx < n_x + n_wq)    { src = (const float4*)wq; dst = wqb; off = idx - n_x; }
  else if (idx < n_x + n_wq + n_wp) { src = (const float4*)wp; dst = wpb; off = idx - n_x - n_wq; }
  else return;
  float4 v = src[off];
  short4 o;
  o.x = f2bf(v.x); o.y = f2bf(v.y); o.z = f2bf(v.z); o.w = f2bf(v.w);
  *(short4*)(dst + (size_t)off * 4) = o;
}

// ---------------- expand relative position bias to [12][208][208] fp32 ----------------
__global__ void rpb_kernel(const float* __restrict__ table, float* __restrict__ rpbf) {
  int idx = blockIdx.x * 256 + threadIdx.x;
  const int tot = NHEADS * NP * NP;
  if (idx >= tot) return;
  int h = idx / (NP * NP);
  int rem = idx - h * NP * NP;
  int i = rem / NP;
  int j = rem - i * NP;
  float v = 0.f;
  if (i < NTOK && j < NTOK) {
    int t;
    if (i == 0 && j == 0) t = 731;
    else if (i == 0)      t = 729;
    else if (j == 0)      t = 730;
    else {
      int p = i - 1, q = j - 1;
      int ri = p / 14, ci = p - ri * 14;
      int rj = q / 14, cj = q - rj * 14;
      t = (ri - rj + 13) * 27 + (ci - cj + 13);
    }
    v = table[t * NHEADS + h];
  }
  rpbf[idx] = v;
}

// ---------------- shared 128x128xK bf16 GEMM mainloop (B^T layout, K=768) ----------------
__device__ inline void gemm_tile_mainloop(const short* __restrict__ A, const short* __restrict__ Bw,
                                          int tm, int tn, short* As, short* Bs,
                                          f32x4 (&acc)[4][4]) {
  const int tid = threadIdx.x;
  const int w = tid >> 6, l = tid & 63, lr = l & 15, lg = l >> 4;
  const int wm = w >> 1, wn = w & 1;
  const int tr = tid >> 1, tc = (tid & 1) * 16;
  const short* Ag = A + (size_t)(tm * 128 + tr) * DIM + tc;
  const short* Bg = Bw + (size_t)(tn * 128 + tr) * DIM + tc;
#pragma unroll
  for (int m = 0; m < 4; ++m)
#pragma unroll
    for (int n = 0; n < 4; ++n) { f32x4 z = {0.f, 0.f, 0.f, 0.f}; acc[m][n] = z; }

  for (int kt = 0; kt < DIM / 32; ++kt) {
    bf16x8 a0 = *(const bf16x8*)(Ag + kt * 32);
    bf16x8 a1 = *(const bf16x8*)(Ag + kt * 32 + 8);
    bf16x8 b0 = *(const bf16x8*)(Bg + kt * 32);
    bf16x8 b1 = *(const bf16x8*)(Bg + kt * 32 + 8);
    __syncthreads();
    *(bf16x8*)(As + tr * 32 + tc)     = a0;
    *(bf16x8*)(As + tr * 32 + tc + 8) = a1;
    *(bf16x8*)(Bs + tr * 32 + tc)     = b0;
    *(bf16x8*)(Bs + tr * 32 + tc + 8) = b1;
    __syncthreads();
    bf16x8 af[4], bfr[4];
#pragma unroll
    for (int m = 0; m < 4; ++m)
      af[m] = *(const bf16x8*)(As + (wm * 64 + m * 16 + lr) * 32 + lg * 8);
#pragma unroll
    for (int n = 0; n < 4; ++n)
      bfr[n] = *(const bf16x8*)(Bs + (wn * 64 + n * 16 + lr) * 32 + lg * 8);
#pragma unroll
    for (int m = 0; m < 4; ++m)
#pragma unroll
      for (int n = 0; n < 4; ++n)
        acc[m][n] = __builtin_amdgcn_mfma_f32_16x16x32_bf16(af[m], bfr[n], acc[m][n], 0, 0, 0);
  }
}

// ---------------- QKV GEMM: epilogue scatters to q/k/v^T head-major buffers ----------------
__global__ void gemm_qkv_kernel(const short* __restrict__ xb, const short* __restrict__ wqb,
                                const float* __restrict__ q_bias, const float* __restrict__ v_bias,
                                short* __restrict__ qbuf, short* __restrict__ kbuf,
                                short* __restrict__ vtbuf) {
  __shared__ __attribute__((aligned(16))) short As[128 * 32];
  __shared__ __attribute__((aligned(16))) short Bs[128 * 32];
  const int bid = blockIdx.x;
  const int tm = bid % 99, tn = bid / 99;  // tn 0..17
  f32x4 acc[4][4];
  gemm_tile_mainloop(xb, wqb, tm, tn, As, Bs, acc);

  const int tid = threadIdx.x;
  const int w = tid >> 6, l = tid & 63, lr = l & 15, lg = l >> 4;
  const int wm = w >> 1, wn = w & 1;
  const int rbase = tm * 128 + wm * 64, cbase = tn * 128 + wn * 64;
#pragma unroll
  for (int n = 0; n < 4; ++n) {
    int c = cbase + n * 16 + lr;
    int part = (c < 768) ? 0 : ((c < 1536) ? 1 : 2);
    int f = c - part * 768;
    int hh = f >> 6, d = f & 63;
    float bias = (part == 0) ? q_bias[c] : ((part == 2) ? v_bias[f] : 0.f);
#pragma unroll
    for (int m = 0; m < 4; ++m) {
#pragma unroll
      for (int i = 0; i < 4; ++i) {
        int r = rbase + m * 16 + lg * 4 + i;
        if (r < M_ROWS) {
          int b = r / 197, nn = r - b * 197;
          int bh = b * 12 + hh;
          float v = acc[m][n][i] + bias;
          if (part == 0)      qbuf[(size_t)(bh * NP + nn) * 64 + d] = f2bf(v * 0.125f);
          else if (part == 1) kbuf[(size_t)(bh * NP + nn) * 64 + d] = f2bf(v);
          else                vtbuf[(size_t)(bh * 64 + d) * NP + nn] = f2bf(v);
        }
      }
    }
  }
}

// ---------------- attention: one block per (b,h) ----------------
__global__ void attn_kernel(const short* __restrict__ qbuf, const short* __restrict__ kbuf,
                            const short* __restrict__ vtbuf, const float* __restrict__ rpbf,
                            short* __restrict__ aout) {
  __shared__ __attribute__((aligned(16))) short Plds[4][16][PS];
  const int bh = blockIdx.x;
  const int b = bh / 12, h = bh - b * 12;
  const short* Q  = qbuf  + (size_t)bh * NP * 64;
  const short* K  = kbuf  + (size_t)bh * NP * 64;
  const short* VT = vtbuf + (size_t)bh * 64 * NP;
  const float* RP = rpbf + (size_t)h * NP * NP;
  const int tid = threadIdx.x;
  const int wave = tid >> 6, l = tid & 63, lr = l & 15, lg = l >> 4;

  for (int s = wave; s < 13; s += 4) {
    const int row0 = s * 16;
    bf16x8 qf0 = *(const bf16x8*)(Q + (row0 + lr) * 64 + lg * 8);
    bf16x8 qf1 = *(const bf16x8*)(Q + (row0 + lr) * 64 + 32 + lg * 8);
    f32x4 acc[13];
#pragma unroll
    for (int t = 0; t < 13; ++t) { f32x4 z = {0.f, 0.f, 0.f, 0.f}; acc[t] = z; }
#pragma unroll
    for (int t = 0; t < 13; ++t) {
      bf16x8 kf0 = *(const bf16x8*)(K + (t * 16 + lr) * 64 + lg * 8);
      bf16x8 kf1 = *(const bf16x8*)(K + (t * 16 + lr) * 64 + 32 + lg * 8);
      acc[t] = __builtin_amdgcn_mfma_f32_16x16x32_bf16(qf0, kf0, acc[t], 0, 0, 0);
      acc[t] = __builtin_amdgcn_mfma_f32_16x16x32_bf16(qf1, kf1, acc[t], 0, 0, 0);
    }
    // ---- softmax over 208 padded cols, rows row0 + lg*4 + i ----
    float sum4[4];
#pragma unroll
    for (int i = 0; i < 4; ++i) {
      const int row = row0 + lg * 4 + i;
      const float* rp = RP + (size_t)row * NP;
      float sv[13];
      float mx = -3e38f;
#pragma unroll
      for (int t = 0; t < 13; ++t) {
        int col = t * 16 + lr;
        float s_ = (col < NTOK) ? (acc[t][i] + rp[col]) : -3e38f;
        sv[t] = s_;
        mx = fmaxf(mx, s_);
      }
      mx = fmaxf(mx, __shfl_xor(mx, 1, 16));
      mx = fmaxf(mx, __shfl_xor(mx, 2, 16));
      mx = fmaxf(mx, __shfl_xor(mx, 4, 16));
      mx = fmaxf(mx, __shfl_xor(mx, 8, 16));
      float sm = 0.f;
#pragma unroll
      for (int t = 0; t < 13; ++t) {
        float p = __expf(sv[t] - mx);
        sm += p;
        Plds[wave][lg * 4 + i][t * 16 + lr] = f2bf(p);
      }
      sm += __shfl_xor(sm, 1, 16);
      sm += __shfl_xor(sm, 2, 16);
      sm += __shfl_xor(sm, 4, 16);
      sm += __shfl_xor(sm, 8, 16);
      sum4[i] = sm;
      Plds[wave][lg * 4 + i][208 + lr] = 0;  // zero pad cols 208..223
    }
    // ---- PV: out strip [16][64] ----
    f32x4 o[4];
#pragma unroll
    for (int dt = 0; dt < 4; ++dt) { f32x4 z = {0.f, 0.f, 0.f, 0.f}; o[dt] = z; }
#pragma unroll
    for (int jb = 0; jb < 7; ++jb) {
      bf16x8 pf = *(const bf16x8*)(&Plds[wave][lr][jb * 32 + lg * 8]);
#pragma unroll
      for (int dt = 0; dt < 4; ++dt) {
        bf16x8 vf = *(const bf16x8*)(VT + (size_t)(dt * 16 + lr) * NP + jb * 32 + lg * 8);
        o[dt] = __builtin_amdgcn_mfma_f32_16x16x32_bf16(pf, vf, o[dt], 0, 0, 0);
      }
    }
    // ---- normalize + store [b, row, h*64 + d] ----
#pragma unroll
    for (int i = 0; i < 4; ++i) {
      const int row = row0 + lg * 4 + i;
      if (row < NTOK) {
        float inv = 1.f / sum4[i];
        size_t base = (size_t)(b * 197 + row) * DIM + h * 64;
#pragma unroll
        for (int dt = 0; dt < 4; ++dt)
          aout[base + dt * 16 + lr] = f2bf(o[dt][i] * inv);
      }
    }
  }
}

// ---------------- proj GEMM: fp32 out + bias ----------------
__global__ void gemm_proj_kernel(const short* __restrict__ ab, const short* __restrict__ wpb,
                                 const float* __restrict__ proj_bias, float* __restrict__ out) {
  __shared__ __attribute__((aligned(16))) short As[128 * 32];
  __shared__ __attribute__((aligned(16))) short Bs[128 * 32];
  const int bid = blockIdx.x;
  const int tm = bid % 99, tn = bid / 99;  // tn 0..5
  f32x4 acc[4][4];
  gemm_tile_mainloop(ab, wpb, tm, tn, As, Bs, acc);

  const int tid = threadIdx.x;
  const int w = tid >> 6, l = tid & 63, lr = l & 15, lg = l >> 4;
  const int wm = w >> 1, wn = w & 1;
  const int rbase = tm * 128 + wm * 64, cbase = tn * 128 + wn * 64;
#pragma unroll
  for (int n = 0; n < 4; ++n) {
    int c = cbase + n * 16 + lr;
    float pb = proj_bias[c];
#pragma unroll
    for (int m = 0; m < 4; ++m) {
#pragma unroll
      for (int i = 0; i < 4; ++i) {
        int r = rbase + m * 16 + lg * 4 + i;
        if (r < M_ROWS) out[(size_t)r * DIM + c] = acc[m][n][i] + pb;
      }
    }
  }
}

extern "C" void kernel_launch(void* const* d_in, const int* in_sizes, int n_in,
                              void* d_out, int out_size, void* d_ws, size_t ws_size,
                              hipStream_t stream) {
  const float* x         = (const float*)d_in[0];
  const float* wqkv      = (const float*)d_in[1];
  const float* q_bias    = (const float*)d_in[2];
  const float* v_bias    = (const float*)d_in[3];
  const float* table     = (const float*)d_in[4];
  const float* wproj     = (const float*)d_in[5];
  const float* proj_bias = (const float*)d_in[6];
  float* out = (float*)d_out;

  char* p = (char*)d_ws;
  short* xb    = (short*)p; p += (size_t)M_PAD * DIM * 2;           // 19,464,192
  short* wqb   = (short*)p; p += (size_t)3 * DIM * DIM * 2;         //  3,538,944
  short* wpb   = (short*)p; p += (size_t)DIM * DIM * 2;             //  1,179,648
  short* qbuf  = (short*)p; p += (size_t)HEADS_TOT * NP * 64 * 2;   // 20,447,232
  short* kbuf  = (short*)p; p += (size_t)HEADS_TOT * NP * 64 * 2;   // 20,447,232
  short* vtbuf = (short*)p; p += (size_t)HEADS_TOT * 64 * NP * 2;   // 20,447,232
  float* rpbf  = (float*)p; p += (size_t)NHEADS * NP * NP * 4;      //  2,076,672
  short* aout  = xb;  // reuse: xb is dead after gemm_qkv

  // zero v^T so (p==0) x pad never multiplies NaN garbage
  hipMemsetAsync(vtbuf, 0, (size_t)HEADS_TOT * 64 * NP * 2, stream);

  const int conv_tot = (M_ROWS * DIM + 3 * DIM * DIM + DIM * DIM) / 4;
  convert_kernel<<<(conv_tot + 255) / 256, 256, 0, stream>>>(x, wqkv, wproj, xb, wqb, wpb);
  rpb_kernel<<<(NHEADS * NP * NP + 255) / 256, 256, 0, stream>>>(table, rpbf);
  gemm_qkv_kernel<<<99 * 18, 256, 0, stream>>>(xb, wqb, q_bias, v_bias, qbuf, kbuf, vtbuf);
  attn_kernel<<<HEADS_TOT, 256, 0, stream>>>(qbuf, kbuf, vtbuf, rpbf, aout);
  gemm_proj_kernel<<<99 * 6, 256, 0, stream>>>(aout, wpb, proj_bias, out);
}

// Round 2
// 190.852 us; speedup vs baseline: 1.5322x; 1.5322x over previous
//
#include <hip/hip_runtime.h>
#include <hip/hip_bf16.h>

#define DIM 768
#define NHEADS 12
#define NTOK 197
#define NP 208         // padded tokens (13*16)
#define NPS 232        // VT / P LDS row stride in shorts (464B: 2-way banks, 16B-divisible)
#define M_ROWS 12608   // B*N
#define M_PAD 12672    // 99*128
#define HEADS_TOT 768  // B*H

typedef __attribute__((ext_vector_type(8))) short bf16x8;
typedef __attribute__((ext_vector_type(4))) float f32x4;

__device__ inline short f2bf(float f) {
  union { __hip_bfloat16 h; short s; } u;
  u.h = __float2bfloat16(f);
  return u.s;
}

__device__ __forceinline__ void gload16(const short* g, short* l) {
  __builtin_amdgcn_global_load_lds((const __attribute__((address_space(1))) void*)g,
                                   (__attribute__((address_space(3))) void*)l, 16, 0, 0);
}

// ---------------- convert fp32 -> bf16 (x, qkv_weight, proj_weight) ----------------
__global__ void convert_kernel(const float* __restrict__ x, const float* __restrict__ wq,
                               const float* __restrict__ wp,
                               short* __restrict__ xb, short* __restrict__ wqb,
                               short* __restrict__ wpb) {
  int idx = blockIdx.x * 256 + threadIdx.x;
  const int n_x  = M_ROWS * DIM / 4;
  const int n_wq = 3 * DIM * DIM / 4;
  const int n_wp = DIM * DIM / 4;
  const float4* src; short* dst; int off;
  if (idx < n_x)                { src = (const float4*)x;  dst = xb;  off = idx; }
  else if (idx < n_x + n_wq)    { src = (const float4*)wq; dst = wqb; off = idx - n_x; }
  else if (idx < n_x + n_wq + n_wp) { src = (const float4*)wp; dst = wpb; off = idx - n_x - n_wq; }
  else return;
  float4 v = src[off];
  short4 o;
  o.x = f2bf(v.x); o.y = f2bf(v.y); o.z = f2bf(v.z); o.w = f2bf(v.w);
  *(short4*)(dst + (size_t)off * 4) = o;
}

// ---------------- expand relative position bias to [12][208][208] fp32 ----------------
__global__ void rpb_kernel(const float* __restrict__ table, float* __restrict__ rpbf) {
  int idx = blockIdx.x * 256 + threadIdx.x;
  const int tot = NHEADS * NP * NP;
  if (idx >= tot) return;
  int h = idx / (NP * NP);
  int rem = idx - h * NP * NP;
  int i = rem / NP;
  int j = rem - i * NP;
  float v = 0.f;
  if (i < NTOK && j < NTOK) {
    int t;
    if (i == 0 && j == 0) t = 731;
    else if (i == 0)      t = 729;
    else if (j == 0)      t = 730;
    else {
      int p = i - 1, q = j - 1;
      int ri = p / 14, ci = p - ri * 14;
      int rj = q / 14, cj = q - rj * 14;
      t = (ri - rj + 13) * 27 + (ci - cj + 13);
    }
    v = table[t * NHEADS + h];
  }
  rpbf[idx] = v;
}

// ---------------- 128x128xK bf16 GEMM mainloop, m97-style global_load_lds staging ----------------
__device__ inline void gemm_tile_mainloop(const short* __restrict__ A, const short* __restrict__ Bw,
                                          int tm, int tn, short* As, short* Bs,
                                          f32x4 (&acc)[4][4]) {
  const int tid = threadIdx.x;
  const int l = tid & 63, lr = l & 15, lg = l >> 4;
  const int w = tid >> 6, wm = w >> 1, wn = w & 1;
  const int row = tid >> 2, c8 = (tid & 3) * 8;   // 64 rows covered per issue
  const short* Ag = A + (size_t)(tm * 128 + row) * DIM + c8;
  const short* Bg = Bw + (size_t)(tn * 128 + row) * DIM + c8;
  short* AsD = As + tid * 8;   // linear LDS: thread t -> bytes t*16 (wave-uniform base + lane*16)
  short* BsD = Bs + tid * 8;
#pragma unroll
  for (int m = 0; m < 4; ++m)
#pragma unroll
    for (int n = 0; n < 4; ++n) { f32x4 z = {0.f, 0.f, 0.f, 0.f}; acc[m][n] = z; }

  for (int kt = 0; kt < DIM / 32; ++kt) {
    __syncthreads();   // protect LDS reads of previous iteration
    gload16(Ag + kt * 32, AsD);
    gload16(Ag + (size_t)64 * DIM + kt * 32, AsD + 2048);
    gload16(Bg + kt * 32, BsD);
    gload16(Bg + (size_t)64 * DIM + kt * 32, BsD + 2048);
    __syncthreads();   // compiler drains vmcnt before barrier -> LDS ready
    bf16x8 af[4], bfr[4];
#pragma unroll
    for (int m = 0; m < 4; ++m)
      af[m] = *(const bf16x8*)(As + (wm * 64 + m * 16 + lr) * 32 + lg * 8);
#pragma unroll
    for (int n = 0; n < 4; ++n)
      bfr[n] = *(const bf16x8*)(Bs + (wn * 64 + n * 16 + lr) * 32 + lg * 8);
#pragma unroll
    for (int m = 0; m < 4; ++m)
#pragma unroll
      for (int n = 0; n < 4; ++n)
        acc[m][n] = __builtin_amdgcn_mfma_f32_16x16x32_bf16(af[m], bfr[n], acc[m][n], 0, 0, 0);
  }
}

// ---------------- QKV GEMM: epilogue scatters to q/k/v^T head-major buffers ----------------
__global__ void gemm_qkv_kernel(const short* __restrict__ xb, const short* __restrict__ wqb,
                                const float* __restrict__ q_bias, const float* __restrict__ v_bias,
                                short* __restrict__ qbuf, short* __restrict__ kbuf,
                                short* __restrict__ vtbuf) {
  __shared__ __attribute__((aligned(16))) short As[128 * 32];
  __shared__ __attribute__((aligned(16))) short Bs[128 * 32];
  const int bid = blockIdx.x;
  const int tm = bid % 99, tn = bid / 99;  // tn 0..17
  f32x4 acc[4][4];
  gemm_tile_mainloop(xb, wqb, tm, tn, As, Bs, acc);

  const int tid = threadIdx.x;
  const int w = tid >> 6, l = tid & 63, lr = l & 15, lg = l >> 4;
  const int wm = w >> 1, wn = w & 1;
  const int rbase = tm * 128 + wm * 64, cbase = tn * 128 + wn * 64;
#pragma unroll
  for (int n = 0; n < 4; ++n) {
    int c = cbase + n * 16 + lr;
    int part = (c < 768) ? 0 : ((c < 1536) ? 1 : 2);
    int f = c - part * 768;
    int hh = f >> 6, d = f & 63;
    float bias = (part == 0) ? q_bias[c] : ((part == 2) ? v_bias[f] : 0.f);
#pragma unroll
    for (int m = 0; m < 4; ++m) {
#pragma unroll
      for (int i = 0; i < 4; ++i) {
        int r = rbase + m * 16 + lg * 4 + i;
        if (r < M_ROWS) {
          int b = r / 197, nn = r - b * 197;
          int bh = b * 12 + hh;
          float v = acc[m][n][i] + bias;
          if (part == 0)      qbuf[(size_t)(bh * NP + nn) * 64 + d] = f2bf(v * 0.125f);
          else if (part == 1) kbuf[(size_t)(bh * NP + nn) * 64 + d] = f2bf(v);
          else                vtbuf[(size_t)(bh * 64 + d) * NP + nn] = f2bf(v);
        }
      }
    }
  }
}

// ---------------- attention: one block (8 waves) per (b,h), K/V^T LDS-resident ----------------
__global__ __launch_bounds__(512, 1)
void attn_kernel(const short* __restrict__ qbuf, const short* __restrict__ kbuf,
                 const short* __restrict__ vtbuf, const float* __restrict__ rpbf,
                 short* __restrict__ aout) {
  __shared__ __attribute__((aligned(16))) short Klds[208 * 64];      // 26,624B XOR-swizzled slots
  __shared__ __attribute__((aligned(16))) short Vlds[64 * NPS];      // 29,696B
  __shared__ __attribute__((aligned(16))) short Plds[8 * 16 * NPS];  // 59,392B (per-wave strips)
  const int bh = blockIdx.x;
  const int b = bh / 12, h = bh - b * 12;
  const short* Qg = qbuf + (size_t)bh * NP * 64;
  const short* Kg = kbuf + (size_t)bh * NP * 64;
  const short* Vg = vtbuf + (size_t)bh * 64 * NP;
  const float* RP = rpbf + (size_t)h * NP * NP;
  const int tid = threadIdx.x;
  const int wave = tid >> 6, l = tid & 63, lr = l & 15, lg = l >> 4;

  // ---- stage K: LDS slot s' holds global slot s'^(r&7)  (linear dest, pre-swizzled src)
  for (int c = tid; c < 1664; c += 512) {               // 1664 = 208*8 chunks; 26 full waves
    int r = c >> 3, sp = c & 7;
    gload16(Kg + r * 64 + ((sp ^ (r & 7)) << 3), Klds + c * 8);
  }
  // ---- stage V^T rows: 29 slots/row (26 data incl tail, 3 dummy), pads fixed after barrier
  for (int c = tid; c < 64 * 29; c += 512) {            // 1856 chunks; 29 full waves
    int r = c / 29, sp = c - r * 29;
    int sg = sp < 26 ? sp : 25;                         // dummy slots read valid in-bounds data
    gload16(Vg + r * NP + sg * 8, Vlds + c * 8);
  }
  __syncthreads();
  // zero V^T cols 197..231 (covers global-unwritten cols and the pad slots)
  if (tid < 64) {
    for (int j = NTOK; j < NPS; ++j) Vlds[tid * NPS + j] = 0;
  }
  __syncthreads();

  short* Pw = Plds + wave * 16 * NPS;
  for (int s = wave; s < 13; s += 8) {
    const int row0 = s * 16;
    bf16x8 qf0 = *(const bf16x8*)(Qg + (row0 + lr) * 64 + lg * 8);
    bf16x8 qf1 = *(const bf16x8*)(Qg + (row0 + lr) * 64 + 32 + lg * 8);
    f32x4 acc[13];
#pragma unroll
    for (int t = 0; t < 13; ++t) { f32x4 z = {0.f, 0.f, 0.f, 0.f}; acc[t] = z; }
    __builtin_amdgcn_s_setprio(1);
#pragma unroll
    for (int t = 0; t < 13; ++t) {
      int rk = t * 16 + lr;
      int sw = lr & 7;
      bf16x8 kf0 = *(const bf16x8*)(Klds + rk * 64 + ((lg ^ sw) << 3));
      bf16x8 kf1 = *(const bf16x8*)(Klds + rk * 64 + (((4 + lg) ^ sw) << 3));
      acc[t] = __builtin_amdgcn_mfma_f32_16x16x32_bf16(qf0, kf0, acc[t], 0, 0, 0);
      acc[t] = __builtin_amdgcn_mfma_f32_16x16x32_bf16(qf1, kf1, acc[t], 0, 0, 0);
    }
    __builtin_amdgcn_s_setprio(0);
    // ---- softmax over 208 padded cols; this lane owns rows row0+lg*4+i, col t*16+lr ----
    float sum4[4];
#pragma unroll
    for (int i = 0; i < 4; ++i) {
      const int row = row0 + lg * 4 + i;
      const float* rp = RP + (size_t)row * NP;
      float sv[13];
      float mx = -3e38f;
#pragma unroll
      for (int t = 0; t < 13; ++t) {
        int col = t * 16 + lr;
        float s_ = (col < NTOK) ? (acc[t][i] + rp[col]) : -3e38f;
        sv[t] = s_;
        mx = fmaxf(mx, s_);
      }
      mx = fmaxf(mx, __shfl_xor(mx, 1, 16));
      mx = fmaxf(mx, __shfl_xor(mx, 2, 16));
      mx = fmaxf(mx, __shfl_xor(mx, 4, 16));
      mx = fmaxf(mx, __shfl_xor(mx, 8, 16));
      float sm = 0.f;
#pragma unroll
      for (int t = 0; t < 13; ++t) {
        float p = __expf(sv[t] - mx);
        sm += p;
        Pw[(lg * 4 + i) * NPS + t * 16 + lr] = f2bf(p);
      }
      sm += __shfl_xor(sm, 1, 16);
      sm += __shfl_xor(sm, 2, 16);
      sm += __shfl_xor(sm, 4, 16);
      sm += __shfl_xor(sm, 8, 16);
      sum4[i] = sm;
      Pw[(lg * 4 + i) * NPS + 208 + lr] = 0;  // zero pad cols 208..223
    }
    // ---- PV: out strip [16][64] ----
    f32x4 o[4];
#pragma unroll
    for (int dt = 0; dt < 4; ++dt) { f32x4 z = {0.f, 0.f, 0.f, 0.f}; o[dt] = z; }
    __builtin_amdgcn_s_setprio(1);
#pragma unroll
    for (int jb = 0; jb < 7; ++jb) {
      bf16x8 pf = *(const bf16x8*)(Pw + lr * NPS + jb * 32 + lg * 8);
#pragma unroll
      for (int dt = 0; dt < 4; ++dt) {
        bf16x8 vf = *(const bf16x8*)(Vlds + (dt * 16 + lr) * NPS + jb * 32 + lg * 8);
        o[dt] = __builtin_amdgcn_mfma_f32_16x16x32_bf16(pf, vf, o[dt], 0, 0, 0);
      }
    }
    __builtin_amdgcn_s_setprio(0);
    // ---- normalize + store [b, row, h*64 + d] ----
#pragma unroll
    for (int i = 0; i < 4; ++i) {
      const int row = row0 + lg * 4 + i;
      if (row < NTOK) {
        float inv = 1.f / sum4[i];
        size_t base = (size_t)(b * 197 + row) * DIM + h * 64;
#pragma unroll
        for (int dt = 0; dt < 4; ++dt)
          aout[base + dt * 16 + lr] = f2bf(o[dt][i] * inv);
      }
    }
  }
}

// ---------------- proj GEMM: fp32 out + bias ----------------
__global__ void gemm_proj_kernel(const short* __restrict__ ab, const short* __restrict__ wpb,
                                 const float* __restrict__ proj_bias, float* __restrict__ out) {
  __shared__ __attribute__((aligned(16))) short As[128 * 32];
  __shared__ __attribute__((aligned(16))) short Bs[128 * 32];
  const int bid = blockIdx.x;
  const int tm = bid % 99, tn = bid / 99;  // tn 0..5
  f32x4 acc[4][4];
  gemm_tile_mainloop(ab, wpb, tm, tn, As, Bs, acc);

  const int tid = threadIdx.x;
  const int w = tid >> 6, l = tid & 63, lr = l & 15, lg = l >> 4;
  const int wm = w >> 1, wn = w & 1;
  const int rbase = tm * 128 + wm * 64, cbase = tn * 128 + wn * 64;
#pragma unroll
  for (int n = 0; n < 4; ++n) {
    int c = cbase + n * 16 + lr;
    float pb = proj_bias[c];
#pragma unroll
    for (int m = 0; m < 4; ++m) {
#pragma unroll
      for (int i = 0; i < 4; ++i) {
        int r = rbase + m * 16 + lg * 4 + i;
        if (r < M_ROWS) out[(size_t)r * DIM + c] = acc[m][n][i] + pb;
      }
    }
  }
}

extern "C" void kernel_launch(void* const* d_in, const int* in_sizes, int n_in,
                              void* d_out, int out_size, void* d_ws, size_t ws_size,
                              hipStream_t stream) {
  const float* x         = (const float*)d_in[0];
  const float* wqkv      = (const float*)d_in[1];
  const float* q_bias    = (const float*)d_in[2];
  const float* v_bias    = (const float*)d_in[3];
  const float* table     = (const float*)d_in[4];
  const float* wproj     = (const float*)d_in[5];
  const float* proj_bias = (const float*)d_in[6];
  float* out = (float*)d_out;

  char* p = (char*)d_ws;
  short* xb    = (short*)p; p += (size_t)M_PAD * DIM * 2;
  short* wqb   = (short*)p; p += (size_t)3 * DIM * DIM * 2;
  short* wpb   = (short*)p; p += (size_t)DIM * DIM * 2;
  short* qbuf  = (short*)p; p += (size_t)HEADS_TOT * NP * 64 * 2;
  short* kbuf  = (short*)p; p += (size_t)HEADS_TOT * NP * 64 * 2;
  short* vtbuf = (short*)p; p += (size_t)HEADS_TOT * 64 * NP * 2;
  float* rpbf  = (float*)p; p += (size_t)NHEADS * NP * NP * 4;
  short* aout  = xb;  // reuse: xb is dead after gemm_qkv

  const int conv_tot = (M_ROWS * DIM + 3 * DIM * DIM + DIM * DIM) / 4;
  convert_kernel<<<(conv_tot + 255) / 256, 256, 0, stream>>>(x, wqkv, wproj, xb, wqb, wpb);
  rpb_kernel<<<(NHEADS * NP * NP + 255) / 256, 256, 0, stream>>>(table, rpbf);
  gemm_qkv_kernel<<<99 * 18, 256, 0, stream>>>(xb, wqb, q_bias, v_bias, qbuf, kbuf, vtbuf);
  attn_kernel<<<HEADS_TOT, 512, 0, stream>>>(qbuf, kbuf, vtbuf, rpbf, aout);
  gemm_proj_kernel<<<99 * 6, 256, 0, stream>>>(aout, wpb, proj_bias, out);
}

// Round 3
// 173.924 us; speedup vs baseline: 1.6813x; 1.0973x over previous
//
#include <hip/hip_runtime.h>
#include <hip/hip_bf16.h>

#define DIM 768
#define NHEADS 12
#define NTOK 197
#define NP 208         // padded tokens (13*16)
#define NPS 232        // VT / P LDS row stride in shorts (464B: 2-way banks, 16B-divisible)
#define M_ROWS 12608   // B*N
#define M_PAD 12672    // 99*128
#define HEADS_TOT 768  // B*H

typedef __attribute__((ext_vector_type(8))) short bf16x8;
typedef __attribute__((ext_vector_type(4))) float f32x4;

__device__ inline short f2bf(float f) {
  union { __hip_bfloat16 h; short s; } u;
  u.h = __float2bfloat16(f);
  return u.s;
}

__device__ __forceinline__ void gload16(const short* g, short* l) {
  __builtin_amdgcn_global_load_lds((const __attribute__((address_space(1))) void*)g,
                                   (__attribute__((address_space(3))) void*)l, 16, 0, 0);
}

// bijective XCD-aware swizzle (m204): each of the 8 XCDs gets one contiguous chunk
__device__ __forceinline__ int xcd_swz(int orig, int nwg) {
  int q = nwg >> 3, r = nwg & 7;
  int x = orig & 7, p = orig >> 3;
  return (x < r ? x * (q + 1) : r * (q + 1) + (x - r) * q) + p;
}

// ---------------- convert fp32 -> bf16 (x, qkv_weight, proj_weight) ----------------
__global__ void convert_kernel(const float* __restrict__ x, const float* __restrict__ wq,
                               const float* __restrict__ wp,
                               short* __restrict__ xb, short* __restrict__ wqb,
                               short* __restrict__ wpb) {
  int idx = blockIdx.x * 256 + threadIdx.x;
  const int n_x  = M_ROWS * DIM / 4;
  const int n_wq = 3 * DIM * DIM / 4;
  const int n_wp = DIM * DIM / 4;
  const float4* src; short* dst; int off;
  if (idx < n_x)                { src = (const float4*)x;  dst = xb;  off = idx; }
  else if (idx < n_x + n_wq)    { src = (const float4*)wq; dst = wqb; off = idx - n_x; }
  else if (idx < n_x + n_wq + n_wp) { src = (const float4*)wp; dst = wpb; off = idx - n_x - n_wq; }
  else return;
  float4 v = src[off];
  short4 o;
  o.x = f2bf(v.x); o.y = f2bf(v.y); o.z = f2bf(v.z); o.w = f2bf(v.w);
  *(short4*)(dst + (size_t)off * 4) = o;
}

// ---------------- expand relative position bias to [12][208][208] fp32 ----------------
__global__ void rpb_kernel(const float* __restrict__ table, float* __restrict__ rpbf) {
  int idx = blockIdx.x * 256 + threadIdx.x;
  const int tot = NHEADS * NP * NP;
  if (idx >= tot) return;
  int h = idx / (NP * NP);
  int rem = idx - h * NP * NP;
  int i = rem / NP;
  int j = rem - i * NP;
  float v = 0.f;
  if (i < NTOK && j < NTOK) {
    int t;
    if (i == 0 && j == 0) t = 731;
    else if (i == 0)      t = 729;
    else if (j == 0)      t = 730;
    else {
      int p = i - 1, q = j - 1;
      int ri = p / 14, ci = p - ri * 14;
      int rj = q / 14, cj = q - rj * 14;
      t = (ri - rj + 13) * 27 + (ci - cj + 13);
    }
    v = table[t * NHEADS + h];
  }
  rpbf[idx] = v;
}

// ---- 128x128xK bf16 GEMM mainloop: double-buffered BK=32, prefetch-before-compute,
// ---- ONE full-drain barrier per K-step (T3-minimum 2-phase recipe).
__device__ inline void gemm_tile_mainloop(const short* __restrict__ A, const short* __restrict__ Bw,
                                          int tm, int tn,
                                          short* As0, short* Bs0, short* As1, short* Bs1,
                                          f32x4 (&acc)[4][4]) {
  const int tid = threadIdx.x;
  const int l = tid & 63, lr = l & 15, lg = l >> 4;
  const int w = tid >> 6, wm = w >> 1, wn = w & 1;
  const int row = tid >> 2, c8 = (tid & 3) * 8;   // 64 rows covered per issue
  const short* Ag = A + (size_t)(tm * 128 + row) * DIM + c8;
  const short* Bg = Bw + (size_t)(tn * 128 + row) * DIM + c8;
  const int dOff = tid * 8;
#pragma unroll
  for (int m = 0; m < 4; ++m)
#pragma unroll
    for (int n = 0; n < 4; ++n) { f32x4 z = {0.f, 0.f, 0.f, 0.f}; acc[m][n] = z; }

  // prologue: stage tile 0 into buffer 0
  gload16(Ag, As0 + dOff);
  gload16(Ag + (size_t)64 * DIM, As0 + 2048 + dOff);
  gload16(Bg, Bs0 + dOff);
  gload16(Bg + (size_t)64 * DIM, Bs0 + 2048 + dOff);
  __syncthreads();   // drains vmcnt(0): tile 0 resident

  const int NT = DIM / 32;  // 24
  for (int kt = 0; kt < NT; ++kt) {
    short* Ac = (kt & 1) ? As1 : As0;
    short* Bc = (kt & 1) ? Bs1 : Bs0;
    short* An = (kt & 1) ? As0 : As1;
    short* Bn = (kt & 1) ? Bs0 : Bs1;
    if (kt < NT - 1) {   // issue next-tile loads FIRST; they fly under the MFMAs below
      gload16(Ag + (kt + 1) * 32, An + dOff);
      gload16(Ag + (size_t)64 * DIM + (kt + 1) * 32, An + 2048 + dOff);
      gload16(Bg + (kt + 1) * 32, Bn + dOff);
      gload16(Bg + (size_t)64 * DIM + (kt + 1) * 32, Bn + 2048 + dOff);
    }
    bf16x8 af[4], bfr[4];
#pragma unroll
    for (int m = 0; m < 4; ++m)
      af[m] = *(const bf16x8*)(Ac + (wm * 64 + m * 16 + lr) * 32 + lg * 8);
#pragma unroll
    for (int n = 0; n < 4; ++n)
      bfr[n] = *(const bf16x8*)(Bc + (wn * 64 + n * 16 + lr) * 32 + lg * 8);
#pragma unroll
    for (int m = 0; m < 4; ++m)
#pragma unroll
      for (int n = 0; n < 4; ++n)
        acc[m][n] = __builtin_amdgcn_mfma_f32_16x16x32_bf16(af[m], bfr[n], acc[m][n], 0, 0, 0);
    __syncthreads();   // one barrier/K-step: drains vmcnt(0) (next tile ready) + lgkm
  }
}

// ---------------- QKV GEMM: epilogue scatters to q/k/v^T head-major buffers ----------------
__global__ void gemm_qkv_kernel(const short* __restrict__ xb, const short* __restrict__ wqb,
                                const float* __restrict__ q_bias, const float* __restrict__ v_bias,
                                short* __restrict__ qbuf, short* __restrict__ kbuf,
                                short* __restrict__ vtbuf) {
  __shared__ __attribute__((aligned(16))) short As0[128 * 32];
  __shared__ __attribute__((aligned(16))) short Bs0[128 * 32];
  __shared__ __attribute__((aligned(16))) short As1[128 * 32];
  __shared__ __attribute__((aligned(16))) short Bs1[128 * 32];
  const int wg = xcd_swz(blockIdx.x, 99 * 18);
  const int tn = wg % 18, tm = wg / 18;   // tn fastest: A-tile L2-reuse across 18 blocks
  f32x4 acc[4][4];
  gemm_tile_mainloop(xb, wqb, tm, tn, As0, Bs0, As1, Bs1, acc);

  const int tid = threadIdx.x;
  const int w = tid >> 6, l = tid & 63, lr = l & 15, lg = l >> 4;
  const int wm = w >> 1, wn = w & 1;
  const int rbase = tm * 128 + wm * 64, cbase = tn * 128 + wn * 64;
#pragma unroll
  for (int n = 0; n < 4; ++n) {
    int c = cbase + n * 16 + lr;
    int part = (c < 768) ? 0 : ((c < 1536) ? 1 : 2);
    int f = c - part * 768;
    int hh = f >> 6, d = f & 63;
    float bias = (part == 0) ? q_bias[c] : ((part == 2) ? v_bias[f] : 0.f);
#pragma unroll
    for (int m = 0; m < 4; ++m) {
#pragma unroll
      for (int i = 0; i < 4; ++i) {
        int r = rbase + m * 16 + lg * 4 + i;
        if (r < M_ROWS) {
          int b = r / 197, nn = r - b * 197;
          int bh = b * 12 + hh;
          float v = acc[m][n][i] + bias;
          if (part == 0)      qbuf[(size_t)(bh * NP + nn) * 64 + d] = f2bf(v * 0.125f);
          else if (part == 1) kbuf[(size_t)(bh * NP + nn) * 64 + d] = f2bf(v);
          else                vtbuf[(size_t)(bh * 64 + d) * NP + nn] = f2bf(v);
        }
      }
    }
  }
}

// ---------------- attention: one block (8 waves) per (b,h), K/V^T LDS-resident ----------------
__global__ __launch_bounds__(512, 1)
void attn_kernel(const short* __restrict__ qbuf, const short* __restrict__ kbuf,
                 const short* __restrict__ vtbuf, const float* __restrict__ rpbf,
                 short* __restrict__ aout) {
  __shared__ __attribute__((aligned(16))) short Klds[208 * 64];      // XOR-swizzled slots
  __shared__ __attribute__((aligned(16))) short Vlds[64 * NPS];
  __shared__ __attribute__((aligned(16))) short Plds[8 * 16 * NPS];
  const int bh = blockIdx.x;
  const int b = bh / 12, h = bh - b * 12;
  const short* Qg = qbuf + (size_t)bh * NP * 64;
  const short* Kg = kbuf + (size_t)bh * NP * 64;
  const short* Vg = vtbuf + (size_t)bh * 64 * NP;
  const float* RP = rpbf + (size_t)h * NP * NP;
  const int tid = threadIdx.x;
  const int wave = tid >> 6, l = tid & 63, lr = l & 15, lg = l >> 4;

  for (int c = tid; c < 1664; c += 512) {
    int r = c >> 3, sp = c & 7;
    gload16(Kg + r * 64 + ((sp ^ (r & 7)) << 3), Klds + c * 8);
  }
  for (int c = tid; c < 64 * 29; c += 512) {
    int r = c / 29, sp = c - r * 29;
    int sg = sp < 26 ? sp : 25;
    gload16(Vg + r * NP + sg * 8, Vlds + c * 8);
  }
  __syncthreads();
  if (tid < 64) {
    for (int j = NTOK; j < NPS; ++j) Vlds[tid * NPS + j] = 0;
  }
  __syncthreads();

  short* Pw = Plds + wave * 16 * NPS;
  for (int s = wave; s < 13; s += 8) {
    const int row0 = s * 16;
    bf16x8 qf0 = *(const bf16x8*)(Qg + (row0 + lr) * 64 + lg * 8);
    bf16x8 qf1 = *(const bf16x8*)(Qg + (row0 + lr) * 64 + 32 + lg * 8);
    f32x4 acc[13];
#pragma unroll
    for (int t = 0; t < 13; ++t) { f32x4 z = {0.f, 0.f, 0.f, 0.f}; acc[t] = z; }
    __builtin_amdgcn_s_setprio(1);
#pragma unroll
    for (int t = 0; t < 13; ++t) {
      int rk = t * 16 + lr;
      int sw = lr & 7;
      bf16x8 kf0 = *(const bf16x8*)(Klds + rk * 64 + ((lg ^ sw) << 3));
      bf16x8 kf1 = *(const bf16x8*)(Klds + rk * 64 + (((4 + lg) ^ sw) << 3));
      acc[t] = __builtin_amdgcn_mfma_f32_16x16x32_bf16(qf0, kf0, acc[t], 0, 0, 0);
      acc[t] = __builtin_amdgcn_mfma_f32_16x16x32_bf16(qf1, kf1, acc[t], 0, 0, 0);
    }
    __builtin_amdgcn_s_setprio(0);
    float sum4[4];
#pragma unroll
    for (int i = 0; i < 4; ++i) {
      const int row = row0 + lg * 4 + i;
      const float* rp = RP + (size_t)row * NP;
      float sv[13];
      float mx = -3e38f;
#pragma unroll
      for (int t = 0; t < 13; ++t) {
        int col = t * 16 + lr;
        float s_ = (col < NTOK) ? (acc[t][i] + rp[col]) : -3e38f;
        sv[t] = s_;
        mx = fmaxf(mx, s_);
      }
      mx = fmaxf(mx, __shfl_xor(mx, 1, 16));
      mx = fmaxf(mx, __shfl_xor(mx, 2, 16));
      mx = fmaxf(mx, __shfl_xor(mx, 4, 16));
      mx = fmaxf(mx, __shfl_xor(mx, 8, 16));
      float sm = 0.f;
#pragma unroll
      for (int t = 0; t < 13; ++t) {
        float p = __expf(sv[t] - mx);
        sm += p;
        Pw[(lg * 4 + i) * NPS + t * 16 + lr] = f2bf(p);
      }
      sm += __shfl_xor(sm, 1, 16);
      sm += __shfl_xor(sm, 2, 16);
      sm += __shfl_xor(sm, 4, 16);
      sm += __shfl_xor(sm, 8, 16);
      sum4[i] = sm;
      Pw[(lg * 4 + i) * NPS + 208 + lr] = 0;
    }
    f32x4 o[4];
#pragma unroll
    for (int dt = 0; dt < 4; ++dt) { f32x4 z = {0.f, 0.f, 0.f, 0.f}; o[dt] = z; }
    __builtin_amdgcn_s_setprio(1);
#pragma unroll
    for (int jb = 0; jb < 7; ++jb) {
      bf16x8 pf = *(const bf16x8*)(Pw + lr * NPS + jb * 32 + lg * 8);
#pragma unroll
      for (int dt = 0; dt < 4; ++dt) {
        bf16x8 vf = *(const bf16x8*)(Vlds + (dt * 16 + lr) * NPS + jb * 32 + lg * 8);
        o[dt] = __builtin_amdgcn_mfma_f32_16x16x32_bf16(pf, vf, o[dt], 0, 0, 0);
      }
    }
    __builtin_amdgcn_s_setprio(0);
#pragma unroll
    for (int i = 0; i < 4; ++i) {
      const int row = row0 + lg * 4 + i;
      if (row < NTOK) {
        float inv = 1.f / sum4[i];
        size_t base = (size_t)(b * 197 + row) * DIM + h * 64;
#pragma unroll
        for (int dt = 0; dt < 4; ++dt)
          aout[base + dt * 16 + lr] = f2bf(o[dt][i] * inv);
      }
    }
  }
}

// ---------------- proj GEMM: fp32 out + bias ----------------
__global__ void gemm_proj_kernel(const short* __restrict__ ab, const short* __restrict__ wpb,
                                 const float* __restrict__ proj_bias, float* __restrict__ out) {
  __shared__ __attribute__((aligned(16))) short As0[128 * 32];
  __shared__ __attribute__((aligned(16))) short Bs0[128 * 32];
  __shared__ __attribute__((aligned(16))) short As1[128 * 32];
  __shared__ __attribute__((aligned(16))) short Bs1[128 * 32];
  const int wg = xcd_swz(blockIdx.x, 99 * 6);
  const int tn = wg % 6, tm = wg / 6;
  f32x4 acc[4][4];
  gemm_tile_mainloop(ab, wpb, tm, tn, As0, Bs0, As1, Bs1, acc);

  const int tid = threadIdx.x;
  const int w = tid >> 6, l = tid & 63, lr = l & 15, lg = l >> 4;
  const int wm = w >> 1, wn = w & 1;
  const int rbase = tm * 128 + wm * 64, cbase = tn * 128 + wn * 64;
#pragma unroll
  for (int n = 0; n < 4; ++n) {
    int c = cbase + n * 16 + lr;
    float pb = proj_bias[c];
#pragma unroll
    for (int m = 0; m < 4; ++m) {
#pragma unroll
      for (int i = 0; i < 4; ++i) {
        int r = rbase + m * 16 + lg * 4 + i;
        if (r < M_ROWS) out[(size_t)r * DIM + c] = acc[m][n][i] + pb;
      }
    }
  }
}

extern "C" void kernel_launch(void* const* d_in, const int* in_sizes, int n_in,
                              void* d_out, int out_size, void* d_ws, size_t ws_size,
                              hipStream_t stream) {
  const float* x         = (const float*)d_in[0];
  const float* wqkv      = (const float*)d_in[1];
  const float* q_bias    = (const float*)d_in[2];
  const float* v_bias    = (const float*)d_in[3];
  const float* table     = (const float*)d_in[4];
  const float* wproj     = (const float*)d_in[5];
  const float* proj_bias = (const float*)d_in[6];
  float* out = (float*)d_out;

  char* p = (char*)d_ws;
  short* xb    = (short*)p; p += (size_t)M_PAD * DIM * 2;
  short* wqb   = (short*)p; p += (size_t)3 * DIM * DIM * 2;
  short* wpb   = (short*)p; p += (size_t)DIM * DIM * 2;
  short* qbuf  = (short*)p; p += (size_t)HEADS_TOT * NP * 64 * 2;
  short* kbuf  = (short*)p; p += (size_t)HEADS_TOT * NP * 64 * 2;
  short* vtbuf = (short*)p; p += (size_t)HEADS_TOT * 64 * NP * 2;
  float* rpbf  = (float*)p; p += (size_t)NHEADS * NP * NP * 4;
  short* aout  = xb;  // reuse: xb is dead after gemm_qkv

  const int conv_tot = (M_ROWS * DIM + 3 * DIM * DIM + DIM * DIM) / 4;
  convert_kernel<<<(conv_tot + 255) / 256, 256, 0, stream>>>(x, wqkv, wproj, xb, wqb, wpb);
  rpb_kernel<<<(NHEADS * NP * NP + 255) / 256, 256, 0, stream>>>(table, rpbf);
  gemm_qkv_kernel<<<99 * 18, 256, 0, stream>>>(xb, wqb, q_bias, v_bias, qbuf, kbuf, vtbuf);
  attn_kernel<<<HEADS_TOT, 512, 0, stream>>>(qbuf, kbuf, vtbuf, rpbf, aout);
  gemm_proj_kernel<<<99 * 6, 256, 0, stream>>>(aout, wpb, proj_bias, out);
}

// Round 4
// 173.635 us; speedup vs baseline: 1.6841x; 1.0017x over previous
//
#include <hip/hip_runtime.h>
#include <hip/hip_bf16.h>

#define DIM 768
#define NHEADS 12
#define NTOK 197
#define NP 208         // padded tokens (13*16)
#define NPS 232        // VT / P LDS row stride in shorts (464B: 2-way banks, 16B-divisible)
#define M_ROWS 12608   // B*N
#define M_PAD 12672    // 99*128
#define HEADS_TOT 768  // B*H

typedef __attribute__((ext_vector_type(8))) short bf16x8;
typedef __attribute__((ext_vector_type(4))) float f32x4;

__device__ inline short f2bf(float f) {
  union { __hip_bfloat16 h; short s; } u;
  u.h = __float2bfloat16(f);
  return u.s;
}

__device__ __forceinline__ void gload16(const short* g, short* l) {
  __builtin_amdgcn_global_load_lds((const __attribute__((address_space(1))) void*)g,
                                   (__attribute__((address_space(3))) void*)l, 16, 0, 0);
}

// bijective XCD-aware swizzle (m204): each of the 8 XCDs gets one contiguous chunk
__device__ __forceinline__ int xcd_swz(int orig, int nwg) {
  int q = nwg >> 3, r = nwg & 7;
  int x = orig & 7, p = orig >> 3;
  return (x < r ? x * (q + 1) : r * (q + 1) + (x - r) * q) + p;
}

// ---------------- convert fp32 -> bf16 (x, qkv_weight, proj_weight) ----------------
__global__ void convert_kernel(const float* __restrict__ x, const float* __restrict__ wq,
                               const float* __restrict__ wp,
                               short* __restrict__ xb, short* __restrict__ wqb,
                               short* __restrict__ wpb) {
  int idx = blockIdx.x * 256 + threadIdx.x;
  const int n_x  = M_ROWS * DIM / 4;
  const int n_wq = 3 * DIM * DIM / 4;
  const int n_wp = DIM * DIM / 4;
  const float4* src; short* dst; int off;
  if (idx < n_x)                { src = (const float4*)x;  dst = xb;  off = idx; }
  else if (idx < n_x + n_wq)    { src = (const float4*)wq; dst = wqb; off = idx - n_x; }
  else if (idx < n_x + n_wq + n_wp) { src = (const float4*)wp; dst = wpb; off = idx - n_x - n_wq; }
  else return;
  float4 v = src[off];
  short4 o;
  o.x = f2bf(v.x); o.y = f2bf(v.y); o.z = f2bf(v.z); o.w = f2bf(v.w);
  *(short4*)(dst + (size_t)off * 4) = o;
}

// ---------------- expand relative position bias to [12][208][208] fp32 ----------------
__global__ void rpb_kernel(const float* __restrict__ table, float* __restrict__ rpbf) {
  int idx = blockIdx.x * 256 + threadIdx.x;
  const int tot = NHEADS * NP * NP;
  if (idx >= tot) return;
  int h = idx / (NP * NP);
  int rem = idx - h * NP * NP;
  int i = rem / NP;
  int j = rem - i * NP;
  float v = 0.f;
  if (i < NTOK && j < NTOK) {
    int t;
    if (i == 0 && j == 0) t = 731;
    else if (i == 0)      t = 729;
    else if (j == 0)      t = 730;
    else {
      int p = i - 1, q = j - 1;
      int ri = p / 14, ci = p - ri * 14;
      int rj = q / 14, cj = q - rj * 14;
      t = (ri - rj + 13) * 27 + (ci - cj + 13);
    }
    v = table[t * NHEADS + h];
  }
  rpbf[idx] = v;
}

// ---- 128x128xK bf16 GEMM mainloop: double-buffered BK=32, prefetch-before-compute,
// ---- ONE full-drain barrier per K-step. T2 XOR-swizzle: LDS 16B-slot s of row r holds
// ---- global K-slot s^((r>>1)&3) (linear gload_lds dest + pre-swizzled source + swizzled read).
__device__ inline void gemm_tile_mainloop(const short* __restrict__ A, const short* __restrict__ Bw,
                                          int tm, int tn,
                                          short* As0, short* Bs0, short* As1, short* Bs1,
                                          f32x4 (&acc)[4][4]) {
  const int tid = threadIdx.x;
  const int l = tid & 63, lr = l & 15, lg = l >> 4;
  const int w = tid >> 6, wm = w >> 1, wn = w & 1;
  const int row = tid >> 2;
  const int c8 = (((tid & 3) ^ ((tid >> 3) & 3)) << 3);   // pre-swizzled source K-slot
  const int rs = (((lg ^ ((lr >> 1) & 3))) << 3);         // swizzled read K-slot
  const short* Ag = A + (size_t)(tm * 128 + row) * DIM + c8;
  const short* Bg = Bw + (size_t)(tn * 128 + row) * DIM + c8;
  const int dOff = tid * 8;
#pragma unroll
  for (int m = 0; m < 4; ++m)
#pragma unroll
    for (int n = 0; n < 4; ++n) { f32x4 z = {0.f, 0.f, 0.f, 0.f}; acc[m][n] = z; }

  // prologue: stage tile 0 into buffer 0
  gload16(Ag, As0 + dOff);
  gload16(Ag + (size_t)64 * DIM, As0 + 2048 + dOff);
  gload16(Bg, Bs0 + dOff);
  gload16(Bg + (size_t)64 * DIM, Bs0 + 2048 + dOff);
  __syncthreads();   // drains vmcnt(0): tile 0 resident

  const int NT = DIM / 32;  // 24
  for (int kt = 0; kt < NT; ++kt) {
    short* Ac = (kt & 1) ? As1 : As0;
    short* Bc = (kt & 1) ? Bs1 : Bs0;
    short* An = (kt & 1) ? As0 : As1;
    short* Bn = (kt & 1) ? Bs0 : Bs1;
    if (kt < NT - 1) {   // issue next-tile loads FIRST; they fly under the MFMAs below
      gload16(Ag + (kt + 1) * 32, An + dOff);
      gload16(Ag + (size_t)64 * DIM + (kt + 1) * 32, An + 2048 + dOff);
      gload16(Bg + (kt + 1) * 32, Bn + dOff);
      gload16(Bg + (size_t)64 * DIM + (kt + 1) * 32, Bn + 2048 + dOff);
    }
    bf16x8 af[4], bfr[4];
#pragma unroll
    for (int m = 0; m < 4; ++m)
      af[m] = *(const bf16x8*)(Ac + (wm * 64 + m * 16 + lr) * 32 + rs);
#pragma unroll
    for (int n = 0; n < 4; ++n)
      bfr[n] = *(const bf16x8*)(Bc + (wn * 64 + n * 16 + lr) * 32 + rs);
#pragma unroll
    for (int m = 0; m < 4; ++m)
#pragma unroll
      for (int n = 0; n < 4; ++n)
        acc[m][n] = __builtin_amdgcn_mfma_f32_16x16x32_bf16(af[m], bfr[n], acc[m][n], 0, 0, 0);
    __syncthreads();   // one barrier/K-step: drains vmcnt(0) (next tile ready) + lgkm
  }
}

// ---------------- QKV GEMM: epilogue scatters to q/k/v^T head-major buffers ----------------
__global__ void gemm_qkv_kernel(const short* __restrict__ xb, const short* __restrict__ wqb,
                                const float* __restrict__ q_bias, const float* __restrict__ v_bias,
                                short* __restrict__ qbuf, short* __restrict__ kbuf,
                                short* __restrict__ vtbuf) {
  __shared__ __attribute__((aligned(16))) short As0[128 * 32];
  __shared__ __attribute__((aligned(16))) short Bs0[128 * 32];
  __shared__ __attribute__((aligned(16))) short As1[128 * 32];
  __shared__ __attribute__((aligned(16))) short Bs1[128 * 32];
  const int wg = xcd_swz(blockIdx.x, 99 * 18);
  const int tn = wg % 18, tm = wg / 18;   // tn fastest: A-tile L2-reuse across 18 blocks
  f32x4 acc[4][4];
  gemm_tile_mainloop(xb, wqb, tm, tn, As0, Bs0, As1, Bs1, acc);

  const int tid = threadIdx.x;
  const int w = tid >> 6, l = tid & 63, lr = l & 15, lg = l >> 4;
  const int wm = w >> 1, wn = w & 1;
  const int rbase = tm * 128 + wm * 64, cbase = tn * 128 + wn * 64;
#pragma unroll
  for (int n = 0; n < 4; ++n) {
    int c = cbase + n * 16 + lr;
    int part = (c < 768) ? 0 : ((c < 1536) ? 1 : 2);
    int f = c - part * 768;
    int hh = f >> 6, d = f & 63;
    float bias = (part == 0) ? q_bias[c] : ((part == 2) ? v_bias[f] : 0.f);
#pragma unroll
    for (int m = 0; m < 4; ++m) {
#pragma unroll
      for (int i = 0; i < 4; ++i) {
        int r = rbase + m * 16 + lg * 4 + i;
        if (r < M_ROWS) {
          int b = r / 197, nn = r - b * 197;
          int bh = b * 12 + hh;
          float v = acc[m][n][i] + bias;
          if (part == 0)      qbuf[(size_t)(bh * NP + nn) * 64 + d] = f2bf(v * 0.125f);
          else if (part == 1) kbuf[(size_t)(bh * NP + nn) * 64 + d] = f2bf(v);
          else                vtbuf[(size_t)(bh * 64 + d) * NP + nn] = f2bf(v);
        }
      }
    }
  }
}

// ---------------- attention: one block (8 waves) per (b,h), K/V^T LDS-resident ----------------
__global__ __launch_bounds__(512, 1)
void attn_kernel(const short* __restrict__ qbuf, const short* __restrict__ kbuf,
                 const short* __restrict__ vtbuf, const float* __restrict__ rpbf,
                 short* __restrict__ aout) {
  __shared__ __attribute__((aligned(16))) short Klds[208 * 64];      // XOR-swizzled slots
  __shared__ __attribute__((aligned(16))) short Vlds[64 * NPS];
  __shared__ __attribute__((aligned(16))) short Plds[8 * 16 * NPS];
  const int bh = blockIdx.x;
  const int b = bh / 12, h = bh - b * 12;
  const short* Qg = qbuf + (size_t)bh * NP * 64;
  const short* Kg = kbuf + (size_t)bh * NP * 64;
  const short* Vg = vtbuf + (size_t)bh * 64 * NP;
  const float* RP = rpbf + (size_t)h * NP * NP;
  const int tid = threadIdx.x;
  const int wave = tid >> 6, l = tid & 63, lr = l & 15, lg = l >> 4;

  for (int c = tid; c < 1664; c += 512) {
    int r = c >> 3, sp = c & 7;
    gload16(Kg + r * 64 + ((sp ^ (r & 7)) << 3), Klds + c * 8);
  }
  for (int c = tid; c < 64 * 29; c += 512) {
    int r = c / 29, sp = c - r * 29;
    int sg = sp < 26 ? sp : 25;
    gload16(Vg + r * NP + sg * 8, Vlds + c * 8);
  }
  __syncthreads();
  if (tid < 64) {
    for (int j = NTOK; j < NPS; ++j) Vlds[tid * NPS + j] = 0;
  }
  __syncthreads();

  short* Pw = Plds + wave * 16 * NPS;
  for (int s = wave; s < 13; s += 8) {
    const int row0 = s * 16;
    bf16x8 qf0 = *(const bf16x8*)(Qg + (row0 + lr) * 64 + lg * 8);
    bf16x8 qf1 = *(const bf16x8*)(Qg + (row0 + lr) * 64 + 32 + lg * 8);
    f32x4 acc[13];
#pragma unroll
    for (int t = 0; t < 13; ++t) { f32x4 z = {0.f, 0.f, 0.f, 0.f}; acc[t] = z; }
    __builtin_amdgcn_s_setprio(1);
#pragma unroll
    for (int t = 0; t < 13; ++t) {
      int rk = t * 16 + lr;
      int sw = lr & 7;
      bf16x8 kf0 = *(const bf16x8*)(Klds + rk * 64 + ((lg ^ sw) << 3));
      bf16x8 kf1 = *(const bf16x8*)(Klds + rk * 64 + (((4 + lg) ^ sw) << 3));
      acc[t] = __builtin_amdgcn_mfma_f32_16x16x32_bf16(qf0, kf0, acc[t], 0, 0, 0);
      acc[t] = __builtin_amdgcn_mfma_f32_16x16x32_bf16(qf1, kf1, acc[t], 0, 0, 0);
    }
    __builtin_amdgcn_s_setprio(0);
    float sum4[4];
#pragma unroll
    for (int i = 0; i < 4; ++i) {
      const int row = row0 + lg * 4 + i;
      const float* rp = RP + (size_t)row * NP;
      float sv[13];
      float mx = -3e38f;
#pragma unroll
      for (int t = 0; t < 13; ++t) {
        int col = t * 16 + lr;
        float s_ = (col < NTOK) ? (acc[t][i] + rp[col]) : -3e38f;
        sv[t] = s_;
        mx = fmaxf(mx, s_);
      }
      mx = fmaxf(mx, __shfl_xor(mx, 1, 16));
      mx = fmaxf(mx, __shfl_xor(mx, 2, 16));
      mx = fmaxf(mx, __shfl_xor(mx, 4, 16));
      mx = fmaxf(mx, __shfl_xor(mx, 8, 16));
      float sm = 0.f;
#pragma unroll
      for (int t = 0; t < 13; ++t) {
        float p = __expf(sv[t] - mx);
        sm += p;
        Pw[(lg * 4 + i) * NPS + t * 16 + lr] = f2bf(p);
      }
      sm += __shfl_xor(sm, 1, 16);
      sm += __shfl_xor(sm, 2, 16);
      sm += __shfl_xor(sm, 4, 16);
      sm += __shfl_xor(sm, 8, 16);
      sum4[i] = sm;
      Pw[(lg * 4 + i) * NPS + 208 + lr] = 0;
    }
    f32x4 o[4];
#pragma unroll
    for (int dt = 0; dt < 4; ++dt) { f32x4 z = {0.f, 0.f, 0.f, 0.f}; o[dt] = z; }
    __builtin_amdgcn_s_setprio(1);
#pragma unroll
    for (int jb = 0; jb < 7; ++jb) {
      bf16x8 pf = *(const bf16x8*)(Pw + lr * NPS + jb * 32 + lg * 8);
#pragma unroll
      for (int dt = 0; dt < 4; ++dt) {
        bf16x8 vf = *(const bf16x8*)(Vlds + (dt * 16 + lr) * NPS + jb * 32 + lg * 8);
        o[dt] = __builtin_amdgcn_mfma_f32_16x16x32_bf16(pf, vf, o[dt], 0, 0, 0);
      }
    }
    __builtin_amdgcn_s_setprio(0);
#pragma unroll
    for (int i = 0; i < 4; ++i) {
      const int row = row0 + lg * 4 + i;
      if (row < NTOK) {
        float inv = 1.f / sum4[i];
        size_t base = (size_t)(b * 197 + row) * DIM + h * 64;
#pragma unroll
        for (int dt = 0; dt < 4; ++dt)
          aout[base + dt * 16 + lr] = f2bf(o[dt][i] * inv);
      }
    }
  }
}

// ---------------- proj GEMM: fp32 out + bias ----------------
__global__ void gemm_proj_kernel(const short* __restrict__ ab, const short* __restrict__ wpb,
                                 const float* __restrict__ proj_bias, float* __restrict__ out) {
  __shared__ __attribute__((aligned(16))) short As0[128 * 32];
  __shared__ __attribute__((aligned(16))) short Bs0[128 * 32];
  __shared__ __attribute__((aligned(16))) short As1[128 * 32];
  __shared__ __attribute__((aligned(16))) short Bs1[128 * 32];
  const int wg = xcd_swz(blockIdx.x, 99 * 6);
  const int tn = wg % 6, tm = wg / 6;
  f32x4 acc[4][4];
  gemm_tile_mainloop(ab, wpb, tm, tn, As0, Bs0, As1, Bs1, acc);

  const int tid = threadIdx.x;
  const int w = tid >> 6, l = tid & 63, lr = l & 15, lg = l >> 4;
  const int wm = w >> 1, wn = w & 1;
  const int rbase = tm * 128 + wm * 64, cbase = tn * 128 + wn * 64;
#pragma unroll
  for (int n = 0; n < 4; ++n) {
    int c = cbase + n * 16 + lr;
    float pb = proj_bias[c];
#pragma unroll
    for (int m = 0; m < 4; ++m) {
#pragma unroll
      for (int i = 0; i < 4; ++i) {
        int r = rbase + m * 16 + lg * 4 + i;
        if (r < M_ROWS) out[(size_t)r * DIM + c] = acc[m][n][i] + pb;
      }
    }
  }
}

extern "C" void kernel_launch(void* const* d_in, const int* in_sizes, int n_in,
                              void* d_out, int out_size, void* d_ws, size_t ws_size,
                              hipStream_t stream) {
  const float* x         = (const float*)d_in[0];
  const float* wqkv      = (const float*)d_in[1];
  const float* q_bias    = (const float*)d_in[2];
  const float* v_bias    = (const float*)d_in[3];
  const float* table     = (const float*)d_in[4];
  const float* wproj     = (const float*)d_in[5];
  const float* proj_bias = (const float*)d_in[6];
  float* out = (float*)d_out;

  char* p = (char*)d_ws;
  short* xb    = (short*)p; p += (size_t)M_PAD * DIM * 2;
  short* wqb   = (short*)p; p += (size_t)3 * DIM * DIM * 2;
  short* wpb   = (short*)p; p += (size_t)DIM * DIM * 2;
  short* qbuf  = (short*)p; p += (size_t)HEADS_TOT * NP * 64 * 2;
  short* kbuf  = (short*)p; p += (size_t)HEADS_TOT * NP * 64 * 2;
  short* vtbuf = (short*)p; p += (size_t)HEADS_TOT * 64 * NP * 2;
  float* rpbf  = (float*)p; p += (size_t)NHEADS * NP * NP * 4;
  short* aout  = xb;  // reuse: xb is dead after gemm_qkv

  const int conv_tot = (M_ROWS * DIM + 3 * DIM * DIM + DIM * DIM) / 4;
  convert_kernel<<<(conv_tot + 255) / 256, 256, 0, stream>>>(x, wqkv, wproj, xb, wqb, wpb);
  rpb_kernel<<<(NHEADS * NP * NP + 255) / 256, 256, 0, stream>>>(table, rpbf);
  gemm_qkv_kernel<<<99 * 18, 256, 0, stream>>>(xb, wqb, q_bias, v_bias, qbuf, kbuf, vtbuf);
  attn_kernel<<<HEADS_TOT, 512, 0, stream>>>(qbuf, kbuf, vtbuf, rpbf, aout);
  gemm_proj_kernel<<<99 * 6, 256, 0, stream>>>(aout, wpb, proj_bias, out);
}